// Round 1
// baseline (10310.316 us; speedup 1.0000x reference)
//
#include <hip/hip_runtime.h>
#include <hip/hip_bf16.h>
#include <math.h>

typedef __bf16 bf16_t;
typedef __bf16 bf16x8 __attribute__((ext_vector_type(8)));
typedef __bf16 bf16x4 __attribute__((ext_vector_type(4)));
typedef float f32x4 __attribute__((ext_vector_type(4)));

// ---------------- np-exact f32 GEMM (encoder) ----------------
// C[M,N] = act(A @ W^T + bias). Each C element = single-accumulator
// ascending-k __fmaf_rn chain (BLAS sgemm semantics), one __fadd_rn bias.
// Tile: (RB*64) x 128, 256 threads.
// Round 11: double-buffered LDS + register prefetch (1 barrier/tile,
// global latency hidden under FMA work) and +4-float LDS row padding
// (stride 132 = 4 mod 32 -> staging transpose stores are 2-way (free)
// instead of 4-way; 132*4B = 0 mod 16 keeps ds_read_b128 alignment).
// Numerics identical: staging layout/order doesn't touch the FMA chain.
template<int ACT, int RB>   // ACT: 0 none, 1 relu;  BM = RB*64
__global__ __launch_bounds__(256, 4)
void np_gemm(const float* __restrict__ A, const float* __restrict__ W,
             const float* __restrict__ bias, float* __restrict__ C,
             int N, int K)
{
    constexpr int LDA = RB * 64 + 4;   // 68 or 132; %32==4, *4B %16==0
    constexpr int LDB = 128 + 4;       // 132
    __shared__ __align__(16) float sA[2][16][LDA];   // [buf][k][m]
    __shared__ __align__(16) float sB[2][16][LDB];   // [buf][k][n]
    const int tid  = threadIdx.x;
    const int tx   = tid & 15, ty = tid >> 4;
    const int bRow = blockIdx.y * (RB * 64), bCol = blockIdx.x * 128;

    float4 acc[RB][2][4];
#pragma unroll
    for (int ib = 0; ib < RB; ++ib)
#pragma unroll
        for (int jb = 0; jb < 2; ++jb)
#pragma unroll
            for (int i = 0; i < 4; ++i)
                acc[ib][jb][i] = make_float4(0.f, 0.f, 0.f, 0.f);

    const int nt = (K + 15) >> 4;

    float4 pa[RB], pb[2];
    // ---- prefetch tile 0 into registers ----
#pragma unroll
    for (int i = 0; i < RB; ++i) {
        int c  = tid + i * 256;
        int r  = c >> 2;
        int kc = (c & 3) << 2;
        pa[i] = make_float4(0.f, 0.f, 0.f, 0.f);
        if (kc < K) pa[i] = *(const float4*)(A + (size_t)(bRow + r) * K + kc);
    }
#pragma unroll
    for (int i = 0; i < 2; ++i) {
        int c  = tid + i * 256;
        int r  = c >> 2;
        int kc = (c & 3) << 2;
        int gr = bCol + r;
        pb[i] = make_float4(0.f, 0.f, 0.f, 0.f);
        if (gr < N && kc < K) pb[i] = *(const float4*)(W + (size_t)gr * K + kc);
    }
    // ---- write tile 0 to buffer 0 ----
#pragma unroll
    for (int i = 0; i < RB; ++i) {
        int c  = tid + i * 256;
        int r  = c >> 2;
        int kc = (c & 3) << 2;
        sA[0][kc + 0][r] = pa[i].x; sA[0][kc + 1][r] = pa[i].y;
        sA[0][kc + 2][r] = pa[i].z; sA[0][kc + 3][r] = pa[i].w;
    }
#pragma unroll
    for (int i = 0; i < 2; ++i) {
        int c  = tid + i * 256;
        int r  = c >> 2;
        int kc = (c & 3) << 2;
        sB[0][kc + 0][r] = pb[i].x; sB[0][kc + 1][r] = pb[i].y;
        sB[0][kc + 2][r] = pb[i].z; sB[0][kc + 3][r] = pb[i].w;
    }
    __syncthreads();

    for (int t = 0; t < nt; ++t) {
        const int cur  = t & 1;
        const int nxt  = cur ^ 1;
        const bool more = (t + 1 < nt);
        const int k0n  = (t + 1) << 4;

        // issue next tile's global loads (latency hides under compute)
        if (more) {
#pragma unroll
            for (int i = 0; i < RB; ++i) {
                int c  = tid + i * 256;
                int r  = c >> 2;
                int kc = (c & 3) << 2;
                int gk = k0n + kc;
                pa[i] = make_float4(0.f, 0.f, 0.f, 0.f);
                if (gk < K) pa[i] = *(const float4*)(A + (size_t)(bRow + r) * K + gk);
            }
#pragma unroll
            for (int i = 0; i < 2; ++i) {
                int c  = tid + i * 256;
                int r  = c >> 2;
                int kc = (c & 3) << 2;
                int gk = k0n + kc;
                int gr = bCol + r;
                pb[i] = make_float4(0.f, 0.f, 0.f, 0.f);
                if (gr < N && gk < K) pb[i] = *(const float4*)(W + (size_t)gr * K + gk);
            }
        }

        // compute current buffer (strictly ascending k -> bit-exact chain)
#pragma unroll
        for (int kk = 0; kk < 16; ++kk) {
            float4 a[RB], b[2];
#pragma unroll
            for (int ib = 0; ib < RB; ++ib)
                a[ib] = *(const float4*)&sA[cur][kk][ib * 64 + ty * 4];
            b[0] = *(const float4*)&sB[cur][kk][tx * 4];
            b[1] = *(const float4*)&sB[cur][kk][64 + tx * 4];
#pragma unroll
            for (int ib = 0; ib < RB; ++ib) {
                float ai[4] = {a[ib].x, a[ib].y, a[ib].z, a[ib].w};
#pragma unroll
                for (int i = 0; i < 4; ++i)
#pragma unroll
                    for (int jb = 0; jb < 2; ++jb) {
                        acc[ib][jb][i].x = __fmaf_rn(ai[i], b[jb].x, acc[ib][jb][i].x);
                        acc[ib][jb][i].y = __fmaf_rn(ai[i], b[jb].y, acc[ib][jb][i].y);
                        acc[ib][jb][i].z = __fmaf_rn(ai[i], b[jb].z, acc[ib][jb][i].z);
                        acc[ib][jb][i].w = __fmaf_rn(ai[i], b[jb].w, acc[ib][jb][i].w);
                    }
            }
        }

        // write next tile to the other buffer (its readers finished at the
        // barrier that ended iteration t-1)
        if (more) {
#pragma unroll
            for (int i = 0; i < RB; ++i) {
                int c  = tid + i * 256;
                int r  = c >> 2;
                int kc = (c & 3) << 2;
                sA[nxt][kc + 0][r] = pa[i].x; sA[nxt][kc + 1][r] = pa[i].y;
                sA[nxt][kc + 2][r] = pa[i].z; sA[nxt][kc + 3][r] = pa[i].w;
            }
#pragma unroll
            for (int i = 0; i < 2; ++i) {
                int c  = tid + i * 256;
                int r  = c >> 2;
                int kc = (c & 3) << 2;
                sB[nxt][kc + 0][r] = pb[i].x; sB[nxt][kc + 1][r] = pb[i].y;
                sB[nxt][kc + 2][r] = pb[i].z; sB[nxt][kc + 3][r] = pb[i].w;
            }
        }
        __syncthreads();
    }

#pragma unroll
    for (int jb = 0; jb < 2; ++jb) {
        int col = bCol + jb * 64 + tx * 4;
        if (col >= N) continue;                 // N%4==0 -> whole float4 in bounds
        float4 bb = *(const float4*)(bias + col);
#pragma unroll
        for (int ib = 0; ib < RB; ++ib)
#pragma unroll
            for (int i = 0; i < 4; ++i) {
                int row = bRow + ib * 64 + ty * 4 + i;
                float4 v = acc[ib][jb][i];
                float4 o;
                o.x = __fadd_rn(v.x, bb.x); o.y = __fadd_rn(v.y, bb.y);
                o.z = __fadd_rn(v.z, bb.z); o.w = __fadd_rn(v.w, bb.w);
                if (ACT == 1) {
                    o.x = o.x > 0.f ? o.x : 0.f; o.y = o.y > 0.f ? o.y : 0.f;
                    o.z = o.z > 0.f ? o.z : 0.f; o.w = o.w > 0.f ? o.w : 0.f;
                }
                *(float4*)(C + (size_t)row * N + col) = o;
            }
    }
}

// ---------------- bf16-split MFMA GEMM (decoder, 4e-3 slack) ----------------
#define BM 128
#define BN 128
#define BKK 32
template<int ACT, int TERMS>
__global__ __launch_bounds__(256)
void gemm_bt(const float* __restrict__ A, const float* __restrict__ W,
             const float* __restrict__ bias,
             float* __restrict__ C0, float* __restrict__ C1,
             int N, int K)
{
    __shared__ __align__(16) bf16_t sA[TERMS][BM][BKK];
    __shared__ __align__(16) bf16_t sB[TERMS][BN][BKK];

    const int tid  = threadIdx.x;
    const int bRow = blockIdx.y * BM;
    const int bCol = blockIdx.x * BN;
    const int wave = tid >> 6;
    const int lane = tid & 63;
    const int wr   = (wave >> 1) * 64;
    const int wc   = (wave & 1) * 64;
    const int quad = lane >> 4;
    const int l15  = lane & 15;

    f32x4 acc[4][4];
#pragma unroll
    for (int i = 0; i < 4; ++i)
#pragma unroll
        for (int j = 0; j < 4; ++j) acc[i][j] = (f32x4){0.f, 0.f, 0.f, 0.f};

    for (int k0 = 0; k0 < K; k0 += BKK) {
        __syncthreads();
#pragma unroll
        for (int i = 0; i < 4; ++i) {
            int c   = tid + i * 256;
            int r   = c >> 3;
            int col = (c & 7) << 2;
            int gk  = k0 + col;
            float4 v = make_float4(0.f, 0.f, 0.f, 0.f);
            if (gk < K) v = *(const float4*)(A + (size_t)(bRow + r) * K + gk);
            float e[4] = {v.x, v.y, v.z, v.w};
#pragma unroll
            for (int t = 0; t < TERMS; ++t) {
                bf16x4 hv;
#pragma unroll
                for (int u = 0; u < 4; ++u) {
                    hv[u] = (bf16_t)e[u];
                    e[u] -= (float)hv[u];
                }
                *(bf16x4*)&sA[t][r][col] = hv;
            }
        }
#pragma unroll
        for (int i = 0; i < 4; ++i) {
            int c   = tid + i * 256;
            int r   = c >> 3;
            int col = (c & 7) << 2;
            int gk  = k0 + col;
            int gr  = bCol + r;
            float4 v = make_float4(0.f, 0.f, 0.f, 0.f);
            if (gr < N && gk < K) v = *(const float4*)(W + (size_t)gr * K + gk);
            float e[4] = {v.x, v.y, v.z, v.w};
#pragma unroll
            for (int t = 0; t < TERMS; ++t) {
                bf16x4 hv;
#pragma unroll
                for (int u = 0; u < 4; ++u) {
                    hv[u] = (bf16_t)e[u];
                    e[u] -= (float)hv[u];
                }
                *(bf16x4*)&sB[t][r][col] = hv;
            }
        }
        __syncthreads();

        bf16x8 af[TERMS][4], bfr[TERMS][4];
#pragma unroll
        for (int t = 0; t < TERMS; ++t)
#pragma unroll
            for (int i = 0; i < 4; ++i) {
                af[t][i]  = *(const bf16x8*)&sA[t][wr + i * 16 + l15][quad * 8];
                bfr[t][i] = *(const bf16x8*)&sB[t][wc + i * 16 + l15][quad * 8];
            }
#pragma unroll
        for (int i = 0; i < 4; ++i)
#pragma unroll
            for (int j = 0; j < 4; ++j)
#pragma unroll
                for (int ta = 0; ta < TERMS; ++ta)
#pragma unroll
                    for (int tb = 0; tb < TERMS - ta; ++tb)
                        acc[i][j] = __builtin_amdgcn_mfma_f32_16x16x32_bf16(
                            af[ta][i], bfr[tb][j], acc[i][j], 0, 0, 0);
    }

#pragma unroll
    for (int j = 0; j < 4; ++j) {
        int col = bCol + wc + j * 16 + l15;
        if (col >= N) continue;
        float bv = bias[col];
#pragma unroll
        for (int i = 0; i < 4; ++i) {
#pragma unroll
            for (int r = 0; r < 4; ++r) {
                int row = bRow + wr + i * 16 + quad * 4 + r;
                float v = acc[i][j][r] + bv;
                if (ACT == 1)      v = v > 0.f ? v : 0.f;
                else if (ACT == 2) v = v >= 0.f ? v : 0.1f * v;
                else if (ACT == 3) v = tanhf(v);
                size_t o = (size_t)row * N + col;
                C0[o] = v;
                if (C1) C1[o] = v;
            }
        }
    }
}

// np-exact nearest scan (bit-identical to np reference; see round 10).
__global__ __launch_bounds__(256)
void k_nearest(const float* __restrict__ Q, const float* __restrict__ C,
               const float* __restrict__ q2a, const float* __restrict__ cn2,
               int chunk, float* __restrict__ pd, int* __restrict__ pi)
{
    __shared__ __align__(16) float sc[64][64];
    __shared__ __align__(16) float sn[64];
    const int tid = threadIdx.x;
    const int q   = blockIdx.x * 256 + tid;
    const int G   = gridDim.y;

    float qr[64];
    const float4* qp = (const float4*)(Q + (size_t)q * 64);
#pragma unroll
    for (int i = 0; i < 16; ++i) ((float4*)qr)[i] = qp[i];
    const float q2 = q2a[q];

    float best = 3.4e38f;
    int   bi   = 0x7fffffff;
    const int c0 = blockIdx.y * chunk;

    for (int cb = 0; cb < chunk; cb += 64) {
        __syncthreads();
        const float4* gp = (const float4*)(C + (size_t)(c0 + cb) * 64);
#pragma unroll
        for (int i = 0; i < 4; ++i) {
            int e = tid + i * 256;
            ((float4*)&sc[0][0])[e] = gp[e];
        }
        if (tid < 64) sn[tid] = cn2[c0 + cb + tid];
        __syncthreads();

        for (int c = 0; c < 64; c += 4) {
            float a0 = 0.f, a1 = 0.f, a2 = 0.f, a3 = 0.f;
            const float4* e0 = (const float4*)&sc[c + 0][0];
            const float4* e1 = (const float4*)&sc[c + 1][0];
            const float4* e2p = (const float4*)&sc[c + 2][0];
            const float4* e3 = (const float4*)&sc[c + 3][0];
#pragma unroll
            for (int z = 0; z < 16; ++z) {          // k ascending, chain order exact
                float4 q4 = ((float4*)qr)[z];
                float4 v0 = e0[z], v1 = e1[z], v2 = e2p[z], v3 = e3[z];
                a0 = __fmaf_rn(q4.x, v0.x, a0); a0 = __fmaf_rn(q4.y, v0.y, a0);
                a0 = __fmaf_rn(q4.z, v0.z, a0); a0 = __fmaf_rn(q4.w, v0.w, a0);
                a1 = __fmaf_rn(q4.x, v1.x, a1); a1 = __fmaf_rn(q4.y, v1.y, a1);
                a1 = __fmaf_rn(q4.z, v1.z, a1); a1 = __fmaf_rn(q4.w, v1.w, a1);
                a2 = __fmaf_rn(q4.x, v2.x, a2); a2 = __fmaf_rn(q4.y, v2.y, a2);
                a2 = __fmaf_rn(q4.z, v2.z, a2); a2 = __fmaf_rn(q4.w, v2.w, a2);
                a3 = __fmaf_rn(q4.x, v3.x, a3); a3 = __fmaf_rn(q4.y, v3.y, a3);
                a3 = __fmaf_rn(q4.z, v3.z, a3); a3 = __fmaf_rn(q4.w, v3.w, a3);
            }
            float d;
            d = __fadd_rn(__fsub_rn(q2, __fmul_rn(2.f, a0)), sn[c + 0]);
            if (d < best) { best = d; bi = c0 + cb + c + 0; }
            d = __fadd_rn(__fsub_rn(q2, __fmul_rn(2.f, a1)), sn[c + 1]);
            if (d < best) { best = d; bi = c0 + cb + c + 1; }
            d = __fadd_rn(__fsub_rn(q2, __fmul_rn(2.f, a2)), sn[c + 2]);
            if (d < best) { best = d; bi = c0 + cb + c + 2; }
            d = __fadd_rn(__fsub_rn(q2, __fmul_rn(2.f, a3)), sn[c + 3]);
            if (d < best) { best = d; bi = c0 + cb + c + 3; }
        }
    }
    pd[(size_t)q * G + blockIdx.y] = best;
    pi[(size_t)q * G + blockIdx.y] = bi;
}

__global__ void k_reduce(const float* __restrict__ pd, const int* __restrict__ pi,
                         int G, int NQ, int* __restrict__ out)
{
    int q = blockIdx.x * blockDim.x + threadIdx.x;
    if (q >= NQ) return;
    float best = 3.4e38f; int bi = 0;
    for (int g = 0; g < G; ++g) {
        float d = pd[(size_t)q * G + g];
        if (d < best) { best = d; bi = pi[(size_t)q * G + g]; }
    }
    out[q] = bi;
}

__global__ void k_gather(const float* __restrict__ src, const int* __restrict__ idx,
                         float* __restrict__ dst, int nsrc)
{
    int r = blockIdx.x, z = threadIdx.x;
    int i = idx[r];
    i = i < 0 ? 0 : (i >= nsrc ? nsrc - 1 : i);
    dst[(size_t)r * 64 + z] = src[(size_t)i * 64 + z];
}

// numpy pairwise row norm^2 (n=64), bit-exact.
__global__ void k_norm2(const float* __restrict__ s, float* __restrict__ o, int rows)
{
    int r0 = blockIdx.x * blockDim.x + threadIdx.x;
    if (r0 >= rows) return;
    const float* p = s + (size_t)r0 * 64;
    float r[8];
#pragma unroll
    for (int j = 0; j < 8; ++j) r[j] = __fmul_rn(p[j], p[j]);
#pragma unroll
    for (int i = 8; i < 64; i += 8)
#pragma unroll
        for (int j = 0; j < 8; ++j)
            r[j] = __fadd_rn(r[j], __fmul_rn(p[i + j], p[i + j]));
    float t01 = __fadd_rn(r[0], r[1]), t23 = __fadd_rn(r[2], r[3]);
    float t45 = __fadd_rn(r[4], r[5]), t67 = __fadd_rn(r[6], r[7]);
    o[r0] = __fadd_rn(__fadd_rn(t01, t23), __fadd_rn(t45, t67));
}

extern "C" void kernel_launch(void* const* d_in, const int* in_sizes, int n_in,
                              void* d_out, int out_size, void* d_ws, size_t ws_size,
                              hipStream_t stream)
{
    const int B  = 16384;
    const int KC = 4096;

    const float* X   = (const float*)d_in[0];
    const float* We1 = (const float*)d_in[1];
    const float* be1 = (const float*)d_in[2];
    const float* We2 = (const float*)d_in[3];
    const float* be2 = (const float*)d_in[4];
    const float* We3 = (const float*)d_in[5];
    const float* be3 = (const float*)d_in[6];
    const float* We4 = (const float*)d_in[7];
    const float* be4 = (const float*)d_in[8];
    const float* emb = (const float*)d_in[9];
    const float* Wd1 = (const float*)d_in[10];
    const float* bd1 = (const float*)d_in[11];
    const float* Wd2 = (const float*)d_in[12];
    const float* bd2 = (const float*)d_in[13];
    const float* Wd3 = (const float*)d_in[14];
    const float* bd3 = (const float*)d_in[15];
    const float* Wd4 = (const float*)d_in[16];
    const float* bd4 = (const float*)d_in[17];

    float* out = (float*)d_out;
    const size_t OFF1 = (size_t)B * 784;
    const size_t OFF2 = OFF1 + (size_t)B * 64;
    const size_t OFF3 = OFF2 + (size_t)B * 784;
    float* zenc = out + OFF1;

    // dynamic batch tiling: pick the largest MQ the workspace can hold
    // (ws_size is constant across calls -> same branch every call, graph-safe)
    const size_t FIXED = (size_t)12 << 20;   // pd/pi/zemb/small + margin
    int MQ;
    if      (ws_size >= FIXED + (size_t)16384 * 7200) MQ = 16384;
    else if (ws_size >= FIXED + (size_t)8192  * 7200) MQ = 8192;
    else                                              MQ = 4096;
    const int NQn = B / MQ;

    char* ws = (char*)d_ws;
    size_t off = 0;
    auto alloc = [&](size_t bytes) -> void* {
        void* p = ws + off;
        off = (off + bytes + 255) & ~(size_t)255;
        return p;
    };
    float* pd    = (float*)alloc((size_t)262144 * 4);
    int*   pi    = (int*)alloc((size_t)262144 * 4);
    int*   idx1  = (int*)alloc((size_t)B * 4);
    int*   idx2  = (int*)alloc((size_t)KC * 4);
    float* e2    = (float*)alloc((size_t)KC * 4);
    float* z2    = (float*)alloc((size_t)B * 4);
    float* zemb  = (float*)alloc((size_t)B * 64 * 4);
    float* h1    = (float*)alloc((size_t)MQ * 1000 * 4);
    float* h2    = (float*)alloc((size_t)MQ * 500 * 4);
    float* h3    = (float*)alloc((size_t)MQ * 300 * 4);
    float* d1f   = h3;
    float* d2f   = h2;
    float* d3f   = h1;

    dim3 blk(256);
    // encoder grids: layer1 RB=2 (128-row tile), layers 2-4 RB=1 (64-row)
    const dim3 eg1(8, MQ / 128), eg2(4, MQ / 64), eg3(3, MQ / 64), eg4(1, MQ / 64);
    // decoder grids (BM=128)
    const dim3 dq1(3, MQ / 128), dq2(4, MQ / 128), dq3(8, MQ / 128), dq4(7, MQ / 128);

    // ---- encoder, np-exact f32 (BLAS-order FMA chains) ----
    for (int q = 0; q < NQn; ++q) {
        const float* Xq = X + (size_t)q * MQ * 784;
        np_gemm<1, 2><<<eg1, blk, 0, stream>>>(Xq, We1, be1, h1, 1000, 784);
        np_gemm<1, 1><<<eg2, blk, 0, stream>>>(h1, We2, be2, h2, 500, 1000);
        np_gemm<1, 1><<<eg3, blk, 0, stream>>>(h2, We3, be3, h3, 300, 500);
        np_gemm<0, 1><<<eg4, blk, 0, stream>>>(h3, We4, be4,
                                               zenc + (size_t)q * MQ * 64, 64, 300);
    }

    // ---- nearest-neighbor: np-exact, no refine ----
    k_norm2<<<dim3((KC + 255) / 256), blk, 0, stream>>>(emb, e2, KC);
    k_norm2<<<dim3((B + 255) / 256),  blk, 0, stream>>>(zenc, z2, B);

    k_nearest<<<dim3(64, 16), blk, 0, stream>>>(zenc, emb, z2, e2, 256, pd, pi);
    k_reduce <<<dim3(B / 256), blk, 0, stream>>>(pd, pi, 16, B, idx1);
    k_gather <<<dim3(B), dim3(64), 0, stream>>>(emb, idx1, zemb, KC);

    k_nearest<<<dim3(16, 64), blk, 0, stream>>>(emb, zenc, e2, z2, 256, pd, pi);
    k_reduce <<<dim3(KC / 256), blk, 0, stream>>>(pd, pi, 64, KC, idx2);
    k_gather <<<dim3(KC), dim3(64), 0, stream>>>(zenc, idx2, out + OFF3, B);

    // ---- decoder; TERMS=2 bf16-split MFMA (4e-3 slack) ----
    for (int q = 0; q < NQn; ++q) {
        const float* zq = zemb + (size_t)q * MQ * 64;
        gemm_bt<2, 2><<<dq1, blk, 0, stream>>>(zq,  Wd1, bd1, d1f, nullptr, 300,  64);
        gemm_bt<2, 2><<<dq2, blk, 0, stream>>>(d1f, Wd2, bd2, d2f, nullptr, 500,  300);
        gemm_bt<2, 2><<<dq3, blk, 0, stream>>>(d2f, Wd3, bd3, d3f, nullptr, 1000, 500);
        gemm_bt<3, 2><<<dq4, blk, 0, stream>>>(d3f, Wd4, bd4,
                                               out + (size_t)q * MQ * 784,
                                               out + OFF2 + (size_t)q * MQ * 784, 784, 1000);
    }

    (void)in_sizes; (void)n_in; (void)out_size;
}

// Round 2
// 1763.491 us; speedup vs baseline: 5.8465x; 5.8465x over previous
//
#include <hip/hip_runtime.h>
#include <hip/hip_bf16.h>
#include <math.h>

typedef __bf16 bf16_t;
typedef __bf16 bf16x8 __attribute__((ext_vector_type(8)));
typedef __bf16 bf16x4 __attribute__((ext_vector_type(4)));
typedef float f32x4 __attribute__((ext_vector_type(4)));

// ---------------- np-exact f32 GEMM (encoder) ----------------
// C[M,N] = act(A @ W^T + bias). Each C element = single-accumulator
// ascending-k __fmaf_rn chain (BLAS sgemm semantics), one __fadd_rn bias.
// Tile: (RB*64) x 128, 256 threads.
// Round 12: double-buffered LDS + register prefetch (1 barrier/tile) and
// +4-float LDS row padding (stride%32==4 -> staging transpose stores are
// 2-way (free) instead of 4-way; stride*4B%16==0 keeps b128 alignment).
// NO min-occupancy launch_bounds: round-11's (256,4) capped VGPR at 64 and
// spilled the 64-reg accumulator to scratch (WRITE_SIZE 65MB->13GB,
// VALUBusy 3.6%). Plain (256) lets the allocator take ~112 VGPR, no spill.
template<int ACT, int RB>   // ACT: 0 none, 1 relu;  BM = RB*64
__global__ __launch_bounds__(256)
void np_gemm(const float* __restrict__ A, const float* __restrict__ W,
             const float* __restrict__ bias, float* __restrict__ C,
             int N, int K)
{
    constexpr int LDA = RB * 64 + 4;   // 68 or 132; %32==4, *4B %16==0
    constexpr int LDB = 128 + 4;       // 132
    __shared__ __align__(16) float sA[2][16][LDA];   // [buf][k][m]
    __shared__ __align__(16) float sB[2][16][LDB];   // [buf][k][n]
    const int tid  = threadIdx.x;
    const int tx   = tid & 15, ty = tid >> 4;
    const int bRow = blockIdx.y * (RB * 64), bCol = blockIdx.x * 128;

    float4 acc[RB][2][4];
#pragma unroll
    for (int ib = 0; ib < RB; ++ib)
#pragma unroll
        for (int jb = 0; jb < 2; ++jb)
#pragma unroll
            for (int i = 0; i < 4; ++i)
                acc[ib][jb][i] = make_float4(0.f, 0.f, 0.f, 0.f);

    const int nt = (K + 15) >> 4;

    float4 pa[RB], pb[2];
    // ---- prefetch tile 0 into registers ----
#pragma unroll
    for (int i = 0; i < RB; ++i) {
        int c  = tid + i * 256;
        int r  = c >> 2;
        int kc = (c & 3) << 2;
        pa[i] = make_float4(0.f, 0.f, 0.f, 0.f);
        if (kc < K) pa[i] = *(const float4*)(A + (size_t)(bRow + r) * K + kc);
    }
#pragma unroll
    for (int i = 0; i < 2; ++i) {
        int c  = tid + i * 256;
        int r  = c >> 2;
        int kc = (c & 3) << 2;
        int gr = bCol + r;
        pb[i] = make_float4(0.f, 0.f, 0.f, 0.f);
        if (gr < N && kc < K) pb[i] = *(const float4*)(W + (size_t)gr * K + kc);
    }
    // ---- write tile 0 to buffer 0 ----
#pragma unroll
    for (int i = 0; i < RB; ++i) {
        int c  = tid + i * 256;
        int r  = c >> 2;
        int kc = (c & 3) << 2;
        sA[0][kc + 0][r] = pa[i].x; sA[0][kc + 1][r] = pa[i].y;
        sA[0][kc + 2][r] = pa[i].z; sA[0][kc + 3][r] = pa[i].w;
    }
#pragma unroll
    for (int i = 0; i < 2; ++i) {
        int c  = tid + i * 256;
        int r  = c >> 2;
        int kc = (c & 3) << 2;
        sB[0][kc + 0][r] = pb[i].x; sB[0][kc + 1][r] = pb[i].y;
        sB[0][kc + 2][r] = pb[i].z; sB[0][kc + 3][r] = pb[i].w;
    }
    __syncthreads();

    for (int t = 0; t < nt; ++t) {
        const int cur  = t & 1;
        const int nxt  = cur ^ 1;
        const bool more = (t + 1 < nt);
        const int k0n  = (t + 1) << 4;

        // issue next tile's global loads (latency hides under compute)
        if (more) {
#pragma unroll
            for (int i = 0; i < RB; ++i) {
                int c  = tid + i * 256;
                int r  = c >> 2;
                int kc = (c & 3) << 2;
                int gk = k0n + kc;
                pa[i] = make_float4(0.f, 0.f, 0.f, 0.f);
                if (gk < K) pa[i] = *(const float4*)(A + (size_t)(bRow + r) * K + gk);
            }
#pragma unroll
            for (int i = 0; i < 2; ++i) {
                int c  = tid + i * 256;
                int r  = c >> 2;
                int kc = (c & 3) << 2;
                int gk = k0n + kc;
                int gr = bCol + r;
                pb[i] = make_float4(0.f, 0.f, 0.f, 0.f);
                if (gr < N && gk < K) pb[i] = *(const float4*)(W + (size_t)gr * K + gk);
            }
        }

        // compute current buffer (strictly ascending k -> bit-exact chain)
#pragma unroll
        for (int kk = 0; kk < 16; ++kk) {
            float4 a[RB], b[2];
#pragma unroll
            for (int ib = 0; ib < RB; ++ib)
                a[ib] = *(const float4*)&sA[cur][kk][ib * 64 + ty * 4];
            b[0] = *(const float4*)&sB[cur][kk][tx * 4];
            b[1] = *(const float4*)&sB[cur][kk][64 + tx * 4];
#pragma unroll
            for (int ib = 0; ib < RB; ++ib) {
                float ai[4] = {a[ib].x, a[ib].y, a[ib].z, a[ib].w};
#pragma unroll
                for (int i = 0; i < 4; ++i)
#pragma unroll
                    for (int jb = 0; jb < 2; ++jb) {
                        acc[ib][jb][i].x = __fmaf_rn(ai[i], b[jb].x, acc[ib][jb][i].x);
                        acc[ib][jb][i].y = __fmaf_rn(ai[i], b[jb].y, acc[ib][jb][i].y);
                        acc[ib][jb][i].z = __fmaf_rn(ai[i], b[jb].z, acc[ib][jb][i].z);
                        acc[ib][jb][i].w = __fmaf_rn(ai[i], b[jb].w, acc[ib][jb][i].w);
                    }
            }
        }

        // write next tile to the other buffer (its readers finished at the
        // barrier that ended iteration t-1)
        if (more) {
#pragma unroll
            for (int i = 0; i < RB; ++i) {
                int c  = tid + i * 256;
                int r  = c >> 2;
                int kc = (c & 3) << 2;
                sA[nxt][kc + 0][r] = pa[i].x; sA[nxt][kc + 1][r] = pa[i].y;
                sA[nxt][kc + 2][r] = pa[i].z; sA[nxt][kc + 3][r] = pa[i].w;
            }
#pragma unroll
            for (int i = 0; i < 2; ++i) {
                int c  = tid + i * 256;
                int r  = c >> 2;
                int kc = (c & 3) << 2;
                sB[nxt][kc + 0][r] = pb[i].x; sB[nxt][kc + 1][r] = pb[i].y;
                sB[nxt][kc + 2][r] = pb[i].z; sB[nxt][kc + 3][r] = pb[i].w;
            }
        }
        __syncthreads();
    }

#pragma unroll
    for (int jb = 0; jb < 2; ++jb) {
        int col = bCol + jb * 64 + tx * 4;
        if (col >= N) continue;                 // N%4==0 -> whole float4 in bounds
        float4 bb = *(const float4*)(bias + col);
#pragma unroll
        for (int ib = 0; ib < RB; ++ib)
#pragma unroll
            for (int i = 0; i < 4; ++i) {
                int row = bRow + ib * 64 + ty * 4 + i;
                float4 v = acc[ib][jb][i];
                float4 o;
                o.x = __fadd_rn(v.x, bb.x); o.y = __fadd_rn(v.y, bb.y);
                o.z = __fadd_rn(v.z, bb.z); o.w = __fadd_rn(v.w, bb.w);
                if (ACT == 1) {
                    o.x = o.x > 0.f ? o.x : 0.f; o.y = o.y > 0.f ? o.y : 0.f;
                    o.z = o.z > 0.f ? o.z : 0.f; o.w = o.w > 0.f ? o.w : 0.f;
                }
                *(float4*)(C + (size_t)row * N + col) = o;
            }
    }
}

// ---------------- bf16-split MFMA GEMM (decoder, 4e-3 slack) ----------------
#define BM 128
#define BN 128
#define BKK 32
template<int ACT, int TERMS>
__global__ __launch_bounds__(256)
void gemm_bt(const float* __restrict__ A, const float* __restrict__ W,
             const float* __restrict__ bias,
             float* __restrict__ C0, float* __restrict__ C1,
             int N, int K)
{
    __shared__ __align__(16) bf16_t sA[TERMS][BM][BKK];
    __shared__ __align__(16) bf16_t sB[TERMS][BN][BKK];

    const int tid  = threadIdx.x;
    const int bRow = blockIdx.y * BM;
    const int bCol = blockIdx.x * BN;
    const int wave = tid >> 6;
    const int lane = tid & 63;
    const int wr   = (wave >> 1) * 64;
    const int wc   = (wave & 1) * 64;
    const int quad = lane >> 4;
    const int l15  = lane & 15;

    f32x4 acc[4][4];
#pragma unroll
    for (int i = 0; i < 4; ++i)
#pragma unroll
        for (int j = 0; j < 4; ++j) acc[i][j] = (f32x4){0.f, 0.f, 0.f, 0.f};

    for (int k0 = 0; k0 < K; k0 += BKK) {
        __syncthreads();
#pragma unroll
        for (int i = 0; i < 4; ++i) {
            int c   = tid + i * 256;
            int r   = c >> 3;
            int col = (c & 7) << 2;
            int gk  = k0 + col;
            float4 v = make_float4(0.f, 0.f, 0.f, 0.f);
            if (gk < K) v = *(const float4*)(A + (size_t)(bRow + r) * K + gk);
            float e[4] = {v.x, v.y, v.z, v.w};
#pragma unroll
            for (int t = 0; t < TERMS; ++t) {
                bf16x4 hv;
#pragma unroll
                for (int u = 0; u < 4; ++u) {
                    hv[u] = (bf16_t)e[u];
                    e[u] -= (float)hv[u];
                }
                *(bf16x4*)&sA[t][r][col] = hv;
            }
        }
#pragma unroll
        for (int i = 0; i < 4; ++i) {
            int c   = tid + i * 256;
            int r   = c >> 3;
            int col = (c & 7) << 2;
            int gk  = k0 + col;
            int gr  = bCol + r;
            float4 v = make_float4(0.f, 0.f, 0.f, 0.f);
            if (gr < N && gk < K) v = *(const float4*)(W + (size_t)gr * K + gk);
            float e[4] = {v.x, v.y, v.z, v.w};
#pragma unroll
            for (int t = 0; t < TERMS; ++t) {
                bf16x4 hv;
#pragma unroll
                for (int u = 0; u < 4; ++u) {
                    hv[u] = (bf16_t)e[u];
                    e[u] -= (float)hv[u];
                }
                *(bf16x4*)&sB[t][r][col] = hv;
            }
        }
        __syncthreads();

        bf16x8 af[TERMS][4], bfr[TERMS][4];
#pragma unroll
        for (int t = 0; t < TERMS; ++t)
#pragma unroll
            for (int i = 0; i < 4; ++i) {
                af[t][i]  = *(const bf16x8*)&sA[t][wr + i * 16 + l15][quad * 8];
                bfr[t][i] = *(const bf16x8*)&sB[t][wc + i * 16 + l15][quad * 8];
            }
#pragma unroll
        for (int i = 0; i < 4; ++i)
#pragma unroll
            for (int j = 0; j < 4; ++j)
#pragma unroll
                for (int ta = 0; ta < TERMS; ++ta)
#pragma unroll
                    for (int tb = 0; tb < TERMS - ta; ++tb)
                        acc[i][j] = __builtin_amdgcn_mfma_f32_16x16x32_bf16(
                            af[ta][i], bfr[tb][j], acc[i][j], 0, 0, 0);
    }

#pragma unroll
    for (int j = 0; j < 4; ++j) {
        int col = bCol + wc + j * 16 + l15;
        if (col >= N) continue;
        float bv = bias[col];
#pragma unroll
        for (int i = 0; i < 4; ++i) {
#pragma unroll
            for (int r = 0; r < 4; ++r) {
                int row = bRow + wr + i * 16 + quad * 4 + r;
                float v = acc[i][j][r] + bv;
                if (ACT == 1)      v = v > 0.f ? v : 0.f;
                else if (ACT == 2) v = v >= 0.f ? v : 0.1f * v;
                else if (ACT == 3) v = tanhf(v);
                size_t o = (size_t)row * N + col;
                C0[o] = v;
                if (C1) C1[o] = v;
            }
        }
    }
}

// np-exact nearest scan (bit-identical to np reference; see round 10).
__global__ __launch_bounds__(256)
void k_nearest(const float* __restrict__ Q, const float* __restrict__ C,
               const float* __restrict__ q2a, const float* __restrict__ cn2,
               int chunk, float* __restrict__ pd, int* __restrict__ pi)
{
    __shared__ __align__(16) float sc[64][64];
    __shared__ __align__(16) float sn[64];
    const int tid = threadIdx.x;
    const int q   = blockIdx.x * 256 + tid;
    const int G   = gridDim.y;

    float qr[64];
    const float4* qp = (const float4*)(Q + (size_t)q * 64);
#pragma unroll
    for (int i = 0; i < 16; ++i) ((float4*)qr)[i] = qp[i];
    const float q2 = q2a[q];

    float best = 3.4e38f;
    int   bi   = 0x7fffffff;
    const int c0 = blockIdx.y * chunk;

    for (int cb = 0; cb < chunk; cb += 64) {
        __syncthreads();
        const float4* gp = (const float4*)(C + (size_t)(c0 + cb) * 64);
#pragma unroll
        for (int i = 0; i < 4; ++i) {
            int e = tid + i * 256;
            ((float4*)&sc[0][0])[e] = gp[e];
        }
        if (tid < 64) sn[tid] = cn2[c0 + cb + tid];
        __syncthreads();

        for (int c = 0; c < 64; c += 4) {
            float a0 = 0.f, a1 = 0.f, a2 = 0.f, a3 = 0.f;
            const float4* e0 = (const float4*)&sc[c + 0][0];
            const float4* e1 = (const float4*)&sc[c + 1][0];
            const float4* e2p = (const float4*)&sc[c + 2][0];
            const float4* e3 = (const float4*)&sc[c + 3][0];
#pragma unroll
            for (int z = 0; z < 16; ++z) {          // k ascending, chain order exact
                float4 q4 = ((float4*)qr)[z];
                float4 v0 = e0[z], v1 = e1[z], v2 = e2p[z], v3 = e3[z];
                a0 = __fmaf_rn(q4.x, v0.x, a0); a0 = __fmaf_rn(q4.y, v0.y, a0);
                a0 = __fmaf_rn(q4.z, v0.z, a0); a0 = __fmaf_rn(q4.w, v0.w, a0);
                a1 = __fmaf_rn(q4.x, v1.x, a1); a1 = __fmaf_rn(q4.y, v1.y, a1);
                a1 = __fmaf_rn(q4.z, v1.z, a1); a1 = __fmaf_rn(q4.w, v1.w, a1);
                a2 = __fmaf_rn(q4.x, v2.x, a2); a2 = __fmaf_rn(q4.y, v2.y, a2);
                a2 = __fmaf_rn(q4.z, v2.z, a2); a2 = __fmaf_rn(q4.w, v2.w, a2);
                a3 = __fmaf_rn(q4.x, v3.x, a3); a3 = __fmaf_rn(q4.y, v3.y, a3);
                a3 = __fmaf_rn(q4.z, v3.z, a3); a3 = __fmaf_rn(q4.w, v3.w, a3);
            }
            float d;
            d = __fadd_rn(__fsub_rn(q2, __fmul_rn(2.f, a0)), sn[c + 0]);
            if (d < best) { best = d; bi = c0 + cb + c + 0; }
            d = __fadd_rn(__fsub_rn(q2, __fmul_rn(2.f, a1)), sn[c + 1]);
            if (d < best) { best = d; bi = c0 + cb + c + 1; }
            d = __fadd_rn(__fsub_rn(q2, __fmul_rn(2.f, a2)), sn[c + 2]);
            if (d < best) { best = d; bi = c0 + cb + c + 2; }
            d = __fadd_rn(__fsub_rn(q2, __fmul_rn(2.f, a3)), sn[c + 3]);
            if (d < best) { best = d; bi = c0 + cb + c + 3; }
        }
    }
    pd[(size_t)q * G + blockIdx.y] = best;
    pi[(size_t)q * G + blockIdx.y] = bi;
}

__global__ void k_reduce(const float* __restrict__ pd, const int* __restrict__ pi,
                         int G, int NQ, int* __restrict__ out)
{
    int q = blockIdx.x * blockDim.x + threadIdx.x;
    if (q >= NQ) return;
    float best = 3.4e38f; int bi = 0;
    for (int g = 0; g < G; ++g) {
        float d = pd[(size_t)q * G + g];
        if (d < best) { best = d; bi = pi[(size_t)q * G + g]; }
    }
    out[q] = bi;
}

__global__ void k_gather(const float* __restrict__ src, const int* __restrict__ idx,
                         float* __restrict__ dst, int nsrc)
{
    int r = blockIdx.x, z = threadIdx.x;
    int i = idx[r];
    i = i < 0 ? 0 : (i >= nsrc ? nsrc - 1 : i);
    dst[(size_t)r * 64 + z] = src[(size_t)i * 64 + z];
}

// numpy pairwise row norm^2 (n=64), bit-exact.
__global__ void k_norm2(const float* __restrict__ s, float* __restrict__ o, int rows)
{
    int r0 = blockIdx.x * blockDim.x + threadIdx.x;
    if (r0 >= rows) return;
    const float* p = s + (size_t)r0 * 64;
    float r[8];
#pragma unroll
    for (int j = 0; j < 8; ++j) r[j] = __fmul_rn(p[j], p[j]);
#pragma unroll
    for (int i = 8; i < 64; i += 8)
#pragma unroll
        for (int j = 0; j < 8; ++j)
            r[j] = __fadd_rn(r[j], __fmul_rn(p[i + j], p[i + j]));
    float t01 = __fadd_rn(r[0], r[1]), t23 = __fadd_rn(r[2], r[3]);
    float t45 = __fadd_rn(r[4], r[5]), t67 = __fadd_rn(r[6], r[7]);
    o[r0] = __fadd_rn(__fadd_rn(t01, t23), __fadd_rn(t45, t67));
}

extern "C" void kernel_launch(void* const* d_in, const int* in_sizes, int n_in,
                              void* d_out, int out_size, void* d_ws, size_t ws_size,
                              hipStream_t stream)
{
    const int B  = 16384;
    const int KC = 4096;

    const float* X   = (const float*)d_in[0];
    const float* We1 = (const float*)d_in[1];
    const float* be1 = (const float*)d_in[2];
    const float* We2 = (const float*)d_in[3];
    const float* be2 = (const float*)d_in[4];
    const float* We3 = (const float*)d_in[5];
    const float* be3 = (const float*)d_in[6];
    const float* We4 = (const float*)d_in[7];
    const float* be4 = (const float*)d_in[8];
    const float* emb = (const float*)d_in[9];
    const float* Wd1 = (const float*)d_in[10];
    const float* bd1 = (const float*)d_in[11];
    const float* Wd2 = (const float*)d_in[12];
    const float* bd2 = (const float*)d_in[13];
    const float* Wd3 = (const float*)d_in[14];
    const float* bd3 = (const float*)d_in[15];
    const float* Wd4 = (const float*)d_in[16];
    const float* bd4 = (const float*)d_in[17];

    float* out = (float*)d_out;
    const size_t OFF1 = (size_t)B * 784;
    const size_t OFF2 = OFF1 + (size_t)B * 64;
    const size_t OFF3 = OFF2 + (size_t)B * 784;
    float* zenc = out + OFF1;

    // dynamic batch tiling: pick the largest MQ the workspace can hold
    // (ws_size is constant across calls -> same branch every call, graph-safe)
    const size_t FIXED = (size_t)12 << 20;   // pd/pi/zemb/small + margin
    int MQ;
    if      (ws_size >= FIXED + (size_t)16384 * 7200) MQ = 16384;
    else if (ws_size >= FIXED + (size_t)8192  * 7200) MQ = 8192;
    else                                              MQ = 4096;
    const int NQn = B / MQ;

    char* ws = (char*)d_ws;
    size_t off = 0;
    auto alloc = [&](size_t bytes) -> void* {
        void* p = ws + off;
        off = (off + bytes + 255) & ~(size_t)255;
        return p;
    };
    float* pd    = (float*)alloc((size_t)262144 * 4);
    int*   pi    = (int*)alloc((size_t)262144 * 4);
    int*   idx1  = (int*)alloc((size_t)B * 4);
    int*   idx2  = (int*)alloc((size_t)KC * 4);
    float* e2    = (float*)alloc((size_t)KC * 4);
    float* z2    = (float*)alloc((size_t)B * 4);
    float* zemb  = (float*)alloc((size_t)B * 64 * 4);
    float* h1    = (float*)alloc((size_t)MQ * 1000 * 4);
    float* h2    = (float*)alloc((size_t)MQ * 500 * 4);
    float* h3    = (float*)alloc((size_t)MQ * 300 * 4);
    float* d1f   = h3;
    float* d2f   = h2;
    float* d3f   = h1;

    dim3 blk(256);
    // encoder grids: layer1 RB=2 (128-row tile), layers 2-4 RB=1 (64-row)
    const dim3 eg1(8, MQ / 128), eg2(4, MQ / 64), eg3(3, MQ / 64), eg4(1, MQ / 64);
    // decoder grids (BM=128)
    const dim3 dq1(3, MQ / 128), dq2(4, MQ / 128), dq3(8, MQ / 128), dq4(7, MQ / 128);

    // ---- encoder, np-exact f32 (BLAS-order FMA chains) ----
    for (int q = 0; q < NQn; ++q) {
        const float* Xq = X + (size_t)q * MQ * 784;
        np_gemm<1, 2><<<eg1, blk, 0, stream>>>(Xq, We1, be1, h1, 1000, 784);
        np_gemm<1, 1><<<eg2, blk, 0, stream>>>(h1, We2, be2, h2, 500, 1000);
        np_gemm<1, 1><<<eg3, blk, 0, stream>>>(h2, We3, be3, h3, 300, 500);
        np_gemm<0, 1><<<eg4, blk, 0, stream>>>(h3, We4, be4,
                                               zenc + (size_t)q * MQ * 64, 64, 300);
    }

    // ---- nearest-neighbor: np-exact, no refine ----
    k_norm2<<<dim3((KC + 255) / 256), blk, 0, stream>>>(emb, e2, KC);
    k_norm2<<<dim3((B + 255) / 256),  blk, 0, stream>>>(zenc, z2, B);

    k_nearest<<<dim3(64, 16), blk, 0, stream>>>(zenc, emb, z2, e2, 256, pd, pi);
    k_reduce <<<dim3(B / 256), blk, 0, stream>>>(pd, pi, 16, B, idx1);
    k_gather <<<dim3(B), dim3(64), 0, stream>>>(emb, idx1, zemb, KC);

    k_nearest<<<dim3(16, 64), blk, 0, stream>>>(emb, zenc, e2, z2, 256, pd, pi);
    k_reduce <<<dim3(KC / 256), blk, 0, stream>>>(pd, pi, 64, KC, idx2);
    k_gather <<<dim3(KC), dim3(64), 0, stream>>>(zenc, idx2, out + OFF3, B);

    // ---- decoder; TERMS=2 bf16-split MFMA (4e-3 slack) ----
    for (int q = 0; q < NQn; ++q) {
        const float* zq = zemb + (size_t)q * MQ * 64;
        gemm_bt<2, 2><<<dq1, blk, 0, stream>>>(zq,  Wd1, bd1, d1f, nullptr, 300,  64);
        gemm_bt<2, 2><<<dq2, blk, 0, stream>>>(d1f, Wd2, bd2, d2f, nullptr, 500,  300);
        gemm_bt<2, 2><<<dq3, blk, 0, stream>>>(d2f, Wd3, bd3, d3f, nullptr, 1000, 500);
        gemm_bt<3, 2><<<dq4, blk, 0, stream>>>(d3f, Wd4, bd4,
                                               out + (size_t)q * MQ * 784,
                                               out + OFF2 + (size_t)q * MQ * 784, 784, 1000);
    }

    (void)in_sizes; (void)n_in; (void)out_size;
}

// Round 3
// 1423.981 us; speedup vs baseline: 7.2405x; 1.2384x over previous
//
#include <hip/hip_runtime.h>
#include <hip/hip_bf16.h>
#include <math.h>

typedef __bf16 bf16_t;
typedef __bf16 bf16x8 __attribute__((ext_vector_type(8)));
typedef __bf16 bf16x4 __attribute__((ext_vector_type(4)));
typedef float f32x4 __attribute__((ext_vector_type(4)));

// async global->LDS, 16B per lane (linear LDS dest = wave base + lane*16)
__device__ __forceinline__ void gload16(const void* g, void* l)
{
    __builtin_amdgcn_global_load_lds(
        (const __attribute__((address_space(1))) void*)g,
        (__attribute__((address_space(3))) void*)l, 16, 0, 0);
}

// ---------------- np-exact f32 GEMM (encoder) ----------------
// Round-0 proven structure (single buffer, 2 barriers/tile, 68 VGPR,
// 2 blocks/CU) + the one proven round-2 improvement: +4-float LDS row
// padding (stride%32==4 -> staging transpose stores 2-way (free) instead
// of 4-way; stride*4B%16==0 keeps float4 alignment). Numerics identical:
// single-accumulator ascending-k __fmaf_rn chain per C element.
// NOTE round-1/2 lesson: double-buffer+reg-prefetch raises VGPR 68->188,
// halves occupancy (2 blocks/CU -> 1) and loses 100us. Do not reintroduce.
template<int ACT, int RB>   // ACT: 0 none, 1 relu;  BM = RB*64
__global__ __launch_bounds__(256)
void np_gemm(const float* __restrict__ A, const float* __restrict__ W,
             const float* __restrict__ bias, float* __restrict__ C,
             int N, int K)
{
    constexpr int LDA = RB * 64 + 4;   // 68 or 132; %32==4, *4B %16==0
    constexpr int LDB = 128 + 4;       // 132
    __shared__ __align__(16) float sA[16][LDA];   // [k][m]
    __shared__ __align__(16) float sB[16][LDB];   // [k][n]
    const int tid  = threadIdx.x;
    const int tx   = tid & 15, ty = tid >> 4;
    const int bRow = blockIdx.y * (RB * 64), bCol = blockIdx.x * 128;

    float4 acc[RB][2][4];
#pragma unroll
    for (int ib = 0; ib < RB; ++ib)
#pragma unroll
        for (int jb = 0; jb < 2; ++jb)
#pragma unroll
            for (int i = 0; i < 4; ++i)
                acc[ib][jb][i] = make_float4(0.f, 0.f, 0.f, 0.f);

    for (int k0 = 0; k0 < K; k0 += 16) {
        __syncthreads();
        // stage A tile (RB*64 rows x 16 k): RB*256 float4 chunks
#pragma unroll
        for (int i = 0; i < RB; ++i) {
            int c  = tid + i * 256;
            int r  = c >> 2;
            int kc = (c & 3) << 2;
            int gk = k0 + kc;
            float4 av = make_float4(0.f, 0.f, 0.f, 0.f);
            if (gk < K) av = *(const float4*)(A + (size_t)(bRow + r) * K + gk);
            sA[kc + 0][r] = av.x; sA[kc + 1][r] = av.y;
            sA[kc + 2][r] = av.z; sA[kc + 3][r] = av.w;
        }
        // stage B tile (128 rows x 16 k): 512 float4 chunks
#pragma unroll
        for (int i = 0; i < 2; ++i) {
            int c  = tid + i * 256;
            int r  = c >> 2;
            int kc = (c & 3) << 2;
            int gk = k0 + kc;
            int gr = bCol + r;
            float4 bv = make_float4(0.f, 0.f, 0.f, 0.f);
            if (gr < N && gk < K) bv = *(const float4*)(W + (size_t)gr * K + gk);
            sB[kc + 0][r] = bv.x; sB[kc + 1][r] = bv.y;
            sB[kc + 2][r] = bv.z; sB[kc + 3][r] = bv.w;
        }
        __syncthreads();

#pragma unroll
        for (int kk = 0; kk < 16; ++kk) {      // strictly ascending k
            float4 a[RB], b[2];
#pragma unroll
            for (int ib = 0; ib < RB; ++ib)
                a[ib] = *(const float4*)&sA[kk][ib * 64 + ty * 4];
            b[0] = *(const float4*)&sB[kk][tx * 4];
            b[1] = *(const float4*)&sB[kk][64 + tx * 4];
#pragma unroll
            for (int ib = 0; ib < RB; ++ib) {
                float ai[4] = {a[ib].x, a[ib].y, a[ib].z, a[ib].w};
#pragma unroll
                for (int i = 0; i < 4; ++i)
#pragma unroll
                    for (int jb = 0; jb < 2; ++jb) {
                        acc[ib][jb][i].x = __fmaf_rn(ai[i], b[jb].x, acc[ib][jb][i].x);
                        acc[ib][jb][i].y = __fmaf_rn(ai[i], b[jb].y, acc[ib][jb][i].y);
                        acc[ib][jb][i].z = __fmaf_rn(ai[i], b[jb].z, acc[ib][jb][i].z);
                        acc[ib][jb][i].w = __fmaf_rn(ai[i], b[jb].w, acc[ib][jb][i].w);
                    }
            }
        }
    }

#pragma unroll
    for (int jb = 0; jb < 2; ++jb) {
        int col = bCol + jb * 64 + tx * 4;
        if (col >= N) continue;                 // N%4==0 -> whole float4 in bounds
        float4 bb = *(const float4*)(bias + col);
#pragma unroll
        for (int ib = 0; ib < RB; ++ib)
#pragma unroll
            for (int i = 0; i < 4; ++i) {
                int row = bRow + ib * 64 + ty * 4 + i;
                float4 v = acc[ib][jb][i];
                float4 o;
                o.x = __fadd_rn(v.x, bb.x); o.y = __fadd_rn(v.y, bb.y);
                o.z = __fadd_rn(v.z, bb.z); o.w = __fadd_rn(v.w, bb.w);
                if (ACT == 1) {
                    o.x = o.x > 0.f ? o.x : 0.f; o.y = o.y > 0.f ? o.y : 0.f;
                    o.z = o.z > 0.f ? o.z : 0.f; o.w = o.w > 0.f ? o.w : 0.f;
                }
                *(float4*)(C + (size_t)row * N + col) = o;
            }
    }
}

// ---------------- split helper: f32 -> (bf16 hi, bf16 lo) planes ----------
// hi = bf16(v), lo = bf16(v - hi): exactly the per-tile split the old
// gemm_bt staging computed -> MFMA inputs bit-identical.
// Writes zero into K-pad and row-pad so unpredicated global_load_lds reads
// of the padded planes stage exact zeros (no garbage, no NaN).
__global__ void k_split(const float* __restrict__ src, bf16_t* __restrict__ hi,
                        bf16_t* __restrict__ lo, int rows, int K, int rowsP, int Kp)
{
    int e = blockIdx.x * 256 + threadIdx.x;
    if (e >= rowsP * Kp) return;
    int r = e / Kp, k = e - r * Kp;
    float v = (r < rows && k < K) ? src[(size_t)r * K + k] : 0.f;
    bf16_t h = (bf16_t)v;
    bf16_t l = (bf16_t)(v - (float)h);
    hi[e] = h; lo[e] = l;
}

// ---------------- bf16 MFMA GEMM on pre-split planes (decoder) ------------
// A and B are pre-split bf16 hi/lo planes (K padded to 32, zero pad).
// Staging = pure copy via global_load_lds width=16 (no VALU repack).
// OUT=0: f32 C0 (stride N) + optional C1.  OUT=1: split bf16 planes
// (stride Kpn, cols [N,Kpn) zero-filled) feeding the next layer.
template<int ACT, int OUT>
__global__ __launch_bounds__(256)
void gemm_planes(const bf16_t* __restrict__ Ahi, const bf16_t* __restrict__ Alo,
                 const bf16_t* __restrict__ Bhi, const bf16_t* __restrict__ Blo,
                 const float* __restrict__ bias,
                 float* __restrict__ C0, float* __restrict__ C1,
                 bf16_t* __restrict__ Phi, bf16_t* __restrict__ Plo,
                 int N, int Kp, int Kpn)
{
    __shared__ __align__(16) bf16_t sA[2][128][32];
    __shared__ __align__(16) bf16_t sB[2][128][32];

    const int tid  = threadIdx.x;
    const int bRow = blockIdx.y * 128;
    const int bCol = blockIdx.x * 128;
    const int wave = tid >> 6;
    const int lane = tid & 63;
    const int wr   = (wave >> 1) * 64;
    const int wc   = (wave & 1) * 64;
    const int quad = lane >> 4;
    const int l15  = lane & 15;

    f32x4 acc[4][4];
#pragma unroll
    for (int i = 0; i < 4; ++i)
#pragma unroll
        for (int j = 0; j < 4; ++j) acc[i][j] = (f32x4){0.f, 0.f, 0.f, 0.f};

    for (int k0 = 0; k0 < Kp; k0 += 32) {
        __syncthreads();
        // stage 4 planes x 8KB; chunk c -> row c>>2, bf16 col (c&3)*8;
        // LDS byte offset = c*16 -> linear in lane (gload_lds requirement)
#pragma unroll
        for (int i = 0; i < 2; ++i) {
            int c    = tid + i * 256;
            int row  = c >> 2;
            int koff = (c & 3) << 3;
            size_t ga = (size_t)(bRow + row) * Kp + (k0 + koff);
            size_t gb = (size_t)(bCol + row) * Kp + (k0 + koff);
            gload16(Ahi + ga, &sA[0][row][koff]);
            gload16(Alo + ga, &sA[1][row][koff]);
            gload16(Bhi + gb, &sB[0][row][koff]);
            gload16(Blo + gb, &sB[1][row][koff]);
        }
        __syncthreads();

        bf16x8 af[2][4], bfr[2][4];
#pragma unroll
        for (int t = 0; t < 2; ++t)
#pragma unroll
            for (int i = 0; i < 4; ++i) {
                af[t][i]  = *(const bf16x8*)&sA[t][wr + i * 16 + l15][quad * 8];
                bfr[t][i] = *(const bf16x8*)&sB[t][wc + i * 16 + l15][quad * 8];
            }
#pragma unroll
        for (int i = 0; i < 4; ++i)
#pragma unroll
            for (int j = 0; j < 4; ++j)
#pragma unroll
                for (int ta = 0; ta < 2; ++ta)
#pragma unroll
                    for (int tb = 0; tb < 2 - ta; ++tb)
                        acc[i][j] = __builtin_amdgcn_mfma_f32_16x16x32_bf16(
                            af[ta][i], bfr[tb][j], acc[i][j], 0, 0, 0);
    }

#pragma unroll
    for (int j = 0; j < 4; ++j) {
        int col = bCol + wc + j * 16 + l15;
        if (OUT == 0) {
            if (col >= N) continue;
            float bv = bias[col];
#pragma unroll
            for (int i = 0; i < 4; ++i)
#pragma unroll
                for (int r = 0; r < 4; ++r) {
                    int row = bRow + wr + i * 16 + quad * 4 + r;
                    float v = acc[i][j][r] + bv;
                    if (ACT == 1)      v = v > 0.f ? v : 0.f;
                    else if (ACT == 2) v = v >= 0.f ? v : 0.1f * v;
                    else if (ACT == 3) v = tanhf(v);
                    size_t o = (size_t)row * N + col;
                    C0[o] = v;
                    if (C1) C1[o] = v;
                }
        } else {
            if (col >= Kpn) continue;
            const bool real = col < N;
            float bv = real ? bias[col] : 0.f;
#pragma unroll
            for (int i = 0; i < 4; ++i)
#pragma unroll
                for (int r = 0; r < 4; ++r) {
                    int row = bRow + wr + i * 16 + quad * 4 + r;
                    float v = 0.f;
                    if (real) {
                        v = acc[i][j][r] + bv;
                        if (ACT == 1)      v = v > 0.f ? v : 0.f;
                        else if (ACT == 2) v = v >= 0.f ? v : 0.1f * v;
                        else if (ACT == 3) v = tanhf(v);
                    }
                    bf16_t h = (bf16_t)v;
                    bf16_t l = (bf16_t)(v - (float)h);
                    size_t o = (size_t)row * Kpn + col;
                    Phi[o] = h; Plo[o] = l;
                }
        }
    }
}

// np-exact nearest scan (bit-identical to np reference; see round 10).
__global__ __launch_bounds__(256)
void k_nearest(const float* __restrict__ Q, const float* __restrict__ C,
               const float* __restrict__ q2a, const float* __restrict__ cn2,
               int chunk, float* __restrict__ pd, int* __restrict__ pi)
{
    __shared__ __align__(16) float sc[64][64];
    __shared__ __align__(16) float sn[64];
    const int tid = threadIdx.x;
    const int q   = blockIdx.x * 256 + tid;
    const int G   = gridDim.y;

    float qr[64];
    const float4* qp = (const float4*)(Q + (size_t)q * 64);
#pragma unroll
    for (int i = 0; i < 16; ++i) ((float4*)qr)[i] = qp[i];
    const float q2 = q2a[q];

    float best = 3.4e38f;
    int   bi   = 0x7fffffff;
    const int c0 = blockIdx.y * chunk;

    for (int cb = 0; cb < chunk; cb += 64) {
        __syncthreads();
        const float4* gp = (const float4*)(C + (size_t)(c0 + cb) * 64);
#pragma unroll
        for (int i = 0; i < 4; ++i) {
            int e = tid + i * 256;
            ((float4*)&sc[0][0])[e] = gp[e];
        }
        if (tid < 64) sn[tid] = cn2[c0 + cb + tid];
        __syncthreads();

        for (int c = 0; c < 64; c += 4) {
            float a0 = 0.f, a1 = 0.f, a2 = 0.f, a3 = 0.f;
            const float4* e0 = (const float4*)&sc[c + 0][0];
            const float4* e1 = (const float4*)&sc[c + 1][0];
            const float4* e2p = (const float4*)&sc[c + 2][0];
            const float4* e3 = (const float4*)&sc[c + 3][0];
#pragma unroll
            for (int z = 0; z < 16; ++z) {          // k ascending, chain order exact
                float4 q4 = ((float4*)qr)[z];
                float4 v0 = e0[z], v1 = e1[z], v2 = e2p[z], v3 = e3[z];
                a0 = __fmaf_rn(q4.x, v0.x, a0); a0 = __fmaf_rn(q4.y, v0.y, a0);
                a0 = __fmaf_rn(q4.z, v0.z, a0); a0 = __fmaf_rn(q4.w, v0.w, a0);
                a1 = __fmaf_rn(q4.x, v1.x, a1); a1 = __fmaf_rn(q4.y, v1.y, a1);
                a1 = __fmaf_rn(q4.z, v1.z, a1); a1 = __fmaf_rn(q4.w, v1.w, a1);
                a2 = __fmaf_rn(q4.x, v2.x, a2); a2 = __fmaf_rn(q4.y, v2.y, a2);
                a2 = __fmaf_rn(q4.z, v2.z, a2); a2 = __fmaf_rn(q4.w, v2.w, a2);
                a3 = __fmaf_rn(q4.x, v3.x, a3); a3 = __fmaf_rn(q4.y, v3.y, a3);
                a3 = __fmaf_rn(q4.z, v3.z, a3); a3 = __fmaf_rn(q4.w, v3.w, a3);
            }
            float d;
            d = __fadd_rn(__fsub_rn(q2, __fmul_rn(2.f, a0)), sn[c + 0]);
            if (d < best) { best = d; bi = c0 + cb + c + 0; }
            d = __fadd_rn(__fsub_rn(q2, __fmul_rn(2.f, a1)), sn[c + 1]);
            if (d < best) { best = d; bi = c0 + cb + c + 1; }
            d = __fadd_rn(__fsub_rn(q2, __fmul_rn(2.f, a2)), sn[c + 2]);
            if (d < best) { best = d; bi = c0 + cb + c + 2; }
            d = __fadd_rn(__fsub_rn(q2, __fmul_rn(2.f, a3)), sn[c + 3]);
            if (d < best) { best = d; bi = c0 + cb + c + 3; }
        }
    }
    pd[(size_t)q * G + blockIdx.y] = best;
    pi[(size_t)q * G + blockIdx.y] = bi;
}

__global__ void k_reduce(const float* __restrict__ pd, const int* __restrict__ pi,
                         int G, int NQ, int* __restrict__ out)
{
    int q = blockIdx.x * blockDim.x + threadIdx.x;
    if (q >= NQ) return;
    float best = 3.4e38f; int bi = 0;
    for (int g = 0; g < G; ++g) {
        float d = pd[(size_t)q * G + g];
        if (d < best) { best = d; bi = pi[(size_t)q * G + g]; }
    }
    out[q] = bi;
}

__global__ void k_gather(const float* __restrict__ src, const int* __restrict__ idx,
                         float* __restrict__ dst, int nsrc)
{
    int r = blockIdx.x, z = threadIdx.x;
    int i = idx[r];
    i = i < 0 ? 0 : (i >= nsrc ? nsrc - 1 : i);
    dst[(size_t)r * 64 + z] = src[(size_t)i * 64 + z];
}

// gather emb rows -> split bf16 planes (decoder layer-1 A input).
// Split of the exact f32 emb values = identical to old per-tile split.
__global__ void k_gather_split(const float* __restrict__ src, const int* __restrict__ idx,
                               bf16_t* __restrict__ hi, bf16_t* __restrict__ lo, int nsrc)
{
    int r = blockIdx.x, z = threadIdx.x;
    int i = idx[r];
    i = i < 0 ? 0 : (i >= nsrc ? nsrc - 1 : i);
    float v = src[(size_t)i * 64 + z];
    bf16_t h = (bf16_t)v;
    bf16_t l = (bf16_t)(v - (float)h);
    hi[(size_t)r * 64 + z] = h;
    lo[(size_t)r * 64 + z] = l;
}

// numpy pairwise row norm^2 (n=64), bit-exact.
__global__ void k_norm2(const float* __restrict__ s, float* __restrict__ o, int rows)
{
    int r0 = blockIdx.x * blockDim.x + threadIdx.x;
    if (r0 >= rows) return;
    const float* p = s + (size_t)r0 * 64;
    float r[8];
#pragma unroll
    for (int j = 0; j < 8; ++j) r[j] = __fmul_rn(p[j], p[j]);
#pragma unroll
    for (int i = 8; i < 64; i += 8)
#pragma unroll
        for (int j = 0; j < 8; ++j)
            r[j] = __fadd_rn(r[j], __fmul_rn(p[i + j], p[i + j]));
    float t01 = __fadd_rn(r[0], r[1]), t23 = __fadd_rn(r[2], r[3]);
    float t45 = __fadd_rn(r[4], r[5]), t67 = __fadd_rn(r[6], r[7]);
    o[r0] = __fadd_rn(__fadd_rn(t01, t23), __fadd_rn(t45, t67));
}

extern "C" void kernel_launch(void* const* d_in, const int* in_sizes, int n_in,
                              void* d_out, int out_size, void* d_ws, size_t ws_size,
                              hipStream_t stream)
{
    const int B  = 16384;
    const int KC = 4096;

    const float* X   = (const float*)d_in[0];
    const float* We1 = (const float*)d_in[1];
    const float* be1 = (const float*)d_in[2];
    const float* We2 = (const float*)d_in[3];
    const float* be2 = (const float*)d_in[4];
    const float* We3 = (const float*)d_in[5];
    const float* be3 = (const float*)d_in[6];
    const float* We4 = (const float*)d_in[7];
    const float* be4 = (const float*)d_in[8];
    const float* emb = (const float*)d_in[9];
    const float* Wd1 = (const float*)d_in[10];
    const float* bd1 = (const float*)d_in[11];
    const float* Wd2 = (const float*)d_in[12];
    const float* bd2 = (const float*)d_in[13];
    const float* Wd3 = (const float*)d_in[14];
    const float* bd3 = (const float*)d_in[15];
    const float* Wd4 = (const float*)d_in[16];
    const float* bd4 = (const float*)d_in[17];

    float* out = (float*)d_out;
    const size_t OFF1 = (size_t)B * 784;
    const size_t OFF2 = OFF1 + (size_t)B * 64;
    const size_t OFF3 = OFF2 + (size_t)B * 784;
    float* zenc = out + OFF1;

    // dynamic batch tiling (ws_size constant across calls -> graph-safe).
    // shared big region per-row budget: max(encoder f32 7200B,
    // decoder planes (320+512+1024)*2*2 = 7424B) = 7424B.
    const size_t FIXED = (size_t)16 << 20;   // pd/pi/idx/zemb planes/weight planes
    int MQ;
    if      (ws_size >= FIXED + (size_t)16384 * 7424) MQ = 16384;
    else if (ws_size >= FIXED + (size_t)8192  * 7424) MQ = 8192;
    else                                              MQ = 4096;
    const int NQn = B / MQ;

    char* ws = (char*)d_ws;
    size_t off = 0;
    auto alloc = [&](size_t bytes) -> void* {
        void* p = ws + off;
        off = (off + bytes + 255) & ~(size_t)255;
        return p;
    };
    float* pd    = (float*)alloc((size_t)262144 * 4);
    int*   pi    = (int*)alloc((size_t)262144 * 4);
    int*   idx1  = (int*)alloc((size_t)B * 4);
    int*   idx2  = (int*)alloc((size_t)KC * 4);
    float* e2    = (float*)alloc((size_t)KC * 4);
    float* z2    = (float*)alloc((size_t)B * 4);
    // split bf16 planes: zemb (full B) + weights (rowsP x Kp, zero-padded)
    bf16_t* zembh = (bf16_t*)alloc((size_t)B * 64 * 2);
    bf16_t* zembl = (bf16_t*)alloc((size_t)B * 64 * 2);
    bf16_t* wp1h = (bf16_t*)alloc((size_t)384 * 64 * 2);
    bf16_t* wp1l = (bf16_t*)alloc((size_t)384 * 64 * 2);
    bf16_t* wp2h = (bf16_t*)alloc((size_t)512 * 320 * 2);
    bf16_t* wp2l = (bf16_t*)alloc((size_t)512 * 320 * 2);
    bf16_t* wp3h = (bf16_t*)alloc((size_t)1024 * 512 * 2);
    bf16_t* wp3l = (bf16_t*)alloc((size_t)1024 * 512 * 2);
    bf16_t* wp4h = (bf16_t*)alloc((size_t)896 * 1024 * 2);
    bf16_t* wp4l = (bf16_t*)alloc((size_t)896 * 1024 * 2);
    // big shared region: encoder f32 h1..h3, then decoder act planes
    char* big = (char*)alloc((size_t)MQ * 7424);
    float* h1 = (float*)big;                           // MQ x 1000 f32
    float* h2 = (float*)(big + (size_t)MQ * 4000);     // MQ x 500
    float* h3 = (float*)(big + (size_t)MQ * 6000);     // MQ x 300
    bf16_t* d1h = (bf16_t*)big;                        // MQ x 320 bf16
    bf16_t* d1l = (bf16_t*)(big + (size_t)MQ * 640);
    bf16_t* d2h = (bf16_t*)(big + (size_t)MQ * 1280);  // MQ x 512
    bf16_t* d2l = (bf16_t*)(big + (size_t)MQ * 2304);
    bf16_t* d3h = (bf16_t*)(big + (size_t)MQ * 3328);  // MQ x 1024
    bf16_t* d3l = (bf16_t*)(big + (size_t)MQ * 5376);

    dim3 blk(256);
    const dim3 eg1(8, MQ / 128), eg2(4, MQ / 64), eg3(3, MQ / 64), eg4(1, MQ / 64);
    const dim3 dq1(3, MQ / 128), dq2(4, MQ / 128), dq3(8, MQ / 128), dq4(7, MQ / 128);

    // ---- decoder weight pre-split (tiny, input-only dependency) ----
    k_split<<<dim3((384 * 64    + 255) / 256), blk, 0, stream>>>(Wd1, wp1h, wp1l, 300, 64, 384, 64);
    k_split<<<dim3((512 * 320   + 255) / 256), blk, 0, stream>>>(Wd2, wp2h, wp2l, 500, 300, 512, 320);
    k_split<<<dim3((1024 * 512  + 255) / 256), blk, 0, stream>>>(Wd3, wp3h, wp3l, 1000, 500, 1024, 512);
    k_split<<<dim3((896 * 1024  + 255) / 256), blk, 0, stream>>>(Wd4, wp4h, wp4l, 784, 1000, 896, 1024);

    // ---- encoder, np-exact f32 (BLAS-order FMA chains) ----
    for (int q = 0; q < NQn; ++q) {
        const float* Xq = X + (size_t)q * MQ * 784;
        np_gemm<1, 2><<<eg1, blk, 0, stream>>>(Xq, We1, be1, h1, 1000, 784);
        np_gemm<1, 1><<<eg2, blk, 0, stream>>>(h1, We2, be2, h2, 500, 1000);
        np_gemm<1, 1><<<eg3, blk, 0, stream>>>(h2, We3, be3, h3, 300, 500);
        np_gemm<0, 1><<<eg4, blk, 0, stream>>>(h3, We4, be4,
                                               zenc + (size_t)q * MQ * 64, 64, 300);
    }

    // ---- nearest-neighbor: np-exact, no refine ----
    k_norm2<<<dim3((KC + 255) / 256), blk, 0, stream>>>(emb, e2, KC);
    k_norm2<<<dim3((B + 255) / 256),  blk, 0, stream>>>(zenc, z2, B);

    k_nearest<<<dim3(64, 16), blk, 0, stream>>>(zenc, emb, z2, e2, 256, pd, pi);
    k_reduce <<<dim3(B / 256), blk, 0, stream>>>(pd, pi, 16, B, idx1);
    k_gather_split<<<dim3(B), dim3(64), 0, stream>>>(emb, idx1, zembh, zembl, KC);

    k_nearest<<<dim3(16, 64), blk, 0, stream>>>(emb, zenc, e2, z2, 256, pd, pi);
    k_reduce <<<dim3(KC / 256), blk, 0, stream>>>(pd, pi, 64, KC, idx2);
    k_gather <<<dim3(KC), dim3(64), 0, stream>>>(zenc, idx2, out + OFF3, B);

    // ---- decoder: pre-split planes + global_load_lds MFMA GEMM ----
    for (int q = 0; q < NQn; ++q) {
        gemm_planes<2, 1><<<dq1, blk, 0, stream>>>(
            zembh + (size_t)q * MQ * 64, zembl + (size_t)q * MQ * 64,
            wp1h, wp1l, bd1, nullptr, nullptr, d1h, d1l, 300, 64, 320);
        gemm_planes<2, 1><<<dq2, blk, 0, stream>>>(
            d1h, d1l, wp2h, wp2l, bd2, nullptr, nullptr, d2h, d2l, 500, 320, 512);
        gemm_planes<2, 1><<<dq3, blk, 0, stream>>>(
            d2h, d2l, wp3h, wp3l, bd3, nullptr, nullptr, d3h, d3l, 1000, 512, 1024);
        gemm_planes<3, 0><<<dq4, blk, 0, stream>>>(
            d3h, d3l, wp4h, wp4l, bd4,
            out + (size_t)q * MQ * 784, out + OFF2 + (size_t)q * MQ * 784,
            nullptr, nullptr, 784, 1024, 0);
    }

    (void)in_sizes; (void)n_in; (void)out_size;
}